// Round 3
// baseline (1101.787 us; speedup 1.0000x reference)
//
#include <hip/hip_runtime.h>
#include <hip/hip_bf16.h>
#include <hip/hip_fp16.h>

// GCN 2-layer: h1 = relu(A_hat (x@W1) + b1); out = log_softmax(A_hat (h1@W2) + b2)
// R3: no CSR. Bucket-partition edges by dst (128 nodes/bucket, packed src<<7|dstLocal),
// then per-bucket fused aggregation with LDS fp32 accumulators (atomic-free globals,
// dense full-line writes). Gather tables h1/h2 in fp16.

#define F1 64
#define F2 16
#define MAXB 1024
#define BSH 128  // nodes per bucket; bucket = dst>>7, local = dst&127

// ---- 1) histogram edges by bucket ----
__global__ void k_hist(const int* __restrict__ dst, int* __restrict__ bcnt,
                       int E, int nb) {
  __shared__ int h[MAXB];
  int t = threadIdx.x;
  for (int i = t; i < MAXB; i += 256) h[i] = 0;
  __syncthreads();
  int chunk = (E + gridDim.x - 1) / gridDim.x;
  int beg = blockIdx.x * chunk;
  int end = min(beg + chunk, E);
  for (int e = beg + t; e < end; e += 256) atomicAdd(&h[dst[e] >> 7], 1);
  __syncthreads();
  for (int i = t; i < nb; i += 256)
    if (h[i]) atomicAdd(&bcnt[i], h[i]);
}

// ---- 2) exclusive scan of bucket counts -> base; init cursor ----
__global__ void k_scanB(const int* __restrict__ bcnt, int* __restrict__ bbase,
                        int* __restrict__ bcur, int nb) {
  __shared__ int lds[MAXB];
  int t = threadIdx.x;  // 1024 threads
  lds[t] = (t < nb) ? bcnt[t] : 0;
  __syncthreads();
  for (int off = 1; off < MAXB; off <<= 1) {
    int add = (t >= off) ? lds[t - off] : 0;
    __syncthreads();
    lds[t] += add;
    __syncthreads();
  }
  if (t < nb) {
    int b = (t == 0) ? 0 : lds[t - 1];
    bbase[t] = b;
    bcur[t] = b;
  }
}

// ---- 3) scatter packed edges into bucket regions (dense per-block runs) ----
__global__ void k_scatter(const int* __restrict__ src, const int* __restrict__ dst,
                          int* __restrict__ bcur, int* __restrict__ tmp,
                          int E, int nb) {
  __shared__ int h[MAXB];
  __shared__ int base[MAXB];
  int t = threadIdx.x;
  for (int i = t; i < MAXB; i += 256) h[i] = 0;
  __syncthreads();
  int chunk = (E + gridDim.x - 1) / gridDim.x;
  int beg = blockIdx.x * chunk;
  int end = min(beg + chunk, E);
  for (int e = beg + t; e < end; e += 256) atomicAdd(&h[dst[e] >> 7], 1);
  __syncthreads();
  for (int i = t; i < nb; i += 256) {
    int c = h[i];
    base[i] = c ? atomicAdd(&bcur[i], c) : 0;
    h[i] = 0;  // reuse as local cursor
  }
  __syncthreads();
  for (int e = beg + t; e < end; e += 256) {
    int d = dst[e];
    int b = d >> 7;
    int off = atomicAdd(&h[b], 1);
    tmp[base[b] + off] = (src[e] << 7) | (d & 127);
  }
}

// ---- 4) per-bucket degree -> dis = rsqrt(deg+1) ----
__global__ void k_bdis(const int* __restrict__ tmp, const int* __restrict__ bbase,
                       const int* __restrict__ bcnt, float* __restrict__ dis, int N) {
  __shared__ int c[BSH];
  int b = blockIdx.x, t = threadIdx.x;
  if (t < BSH) c[t] = 0;
  __syncthreads();
  int beg = bbase[b], end = beg + bcnt[b];
  for (int e = beg + t; e < end; e += 256) atomicAdd(&c[tmp[e] & 127], 1);
  __syncthreads();
  if (t < BSH) {
    int n = b * BSH + t;
    if (n < N) dis[n] = rsqrtf((float)(c[t] + 1));
  }
}

// ---- GEMM1: h1[N,64] = x[N,64] @ W1[64,64], fp16 out (bias after agg) ----
__global__ void k_gemm1(const float* __restrict__ x, const float* __restrict__ W,
                        __half* __restrict__ out, int N) {
  __shared__ float w[64 * 64];
  for (int i = threadIdx.x; i < 64 * 64; i += 256) w[i] = W[i];
  __syncthreads();
  int lane = threadIdx.x & 63;
  int wv = threadIdx.x >> 6;
  for (int n = blockIdx.x * 4 + wv; n < N; n += gridDim.x * 4) {
    const float4* xr = (const float4*)(x + (size_t)n * 64);
    float acc = 0.f;
#pragma unroll
    for (int k4 = 0; k4 < 16; ++k4) {
      float4 xv = xr[k4];
      acc = fmaf(xv.x, w[(k4 * 4 + 0) * 64 + lane], acc);
      acc = fmaf(xv.y, w[(k4 * 4 + 1) * 64 + lane], acc);
      acc = fmaf(xv.z, w[(k4 * 4 + 2) * 64 + lane], acc);
      acc = fmaf(xv.w, w[(k4 * 4 + 3) * 64 + lane], acc);
    }
    out[(size_t)n * 64 + lane] = __float2half(acc);
  }
}

// ---- fused agg layer 1: block = bucket, LDS acc[128][64], bias+relu epilogue ----
__global__ void k_agg1(const __half* __restrict__ h1, const float* __restrict__ dis,
                       const int* __restrict__ tmp, const int* __restrict__ bbase,
                       const int* __restrict__ bcnt, const float* __restrict__ b1,
                       float* __restrict__ hr, int N) {
  __shared__ float acc[BSH][64];
  int b = blockIdx.x, t = threadIdx.x;
  int lane = t & 63, wv = t >> 6;
  float bias = b1[lane];
  // init with self-loop term dis[n]*h1[n]
  for (int l = wv; l < BSH; l += 4) {
    int n = b * BSH + l;
    acc[l][lane] = (n < N) ? dis[n] * __half2float(h1[(size_t)n * 64 + lane]) : 0.f;
  }
  __syncthreads();
  int beg = bbase[b], end = beg + bcnt[b];
  // wave wv owns chunks [beg+wv*4, +4) stepping 16; 4-deep MLP
  int e = beg + wv * 4;
  for (; e + 4 <= end; e += 16) {
    int p0 = tmp[e], p1 = tmp[e + 1], p2 = tmp[e + 2], p3 = tmp[e + 3];
    int s0 = p0 >> 7, s1 = p1 >> 7, s2 = p2 >> 7, s3 = p3 >> 7;
    float v0 = dis[s0] * __half2float(h1[(size_t)s0 * 64 + lane]);
    float v1 = dis[s1] * __half2float(h1[(size_t)s1 * 64 + lane]);
    float v2 = dis[s2] * __half2float(h1[(size_t)s2 * 64 + lane]);
    float v3 = dis[s3] * __half2float(h1[(size_t)s3 * 64 + lane]);
    atomicAdd(&acc[p0 & 127][lane], v0);
    atomicAdd(&acc[p1 & 127][lane], v1);
    atomicAdd(&acc[p2 & 127][lane], v2);
    atomicAdd(&acc[p3 & 127][lane], v3);
  }
  for (; e < end; ++e) {  // truncated tail of this wave's chunk
    int p = tmp[e];
    int s = p >> 7;
    atomicAdd(&acc[p & 127][lane], dis[s] * __half2float(h1[(size_t)s * 64 + lane]));
  }
  __syncthreads();
  for (int l = wv; l < BSH; l += 4) {
    int n = b * BSH + l;
    if (n < N) {
      float v = fmaf(dis[n], acc[l][lane], bias);
      hr[(size_t)n * 64 + lane] = fmaxf(v, 0.f);
    }
  }
}

// ---- GEMM2: h2[N,16] = hr[N,64] @ W2[64,16], fp16 out ----
__global__ void k_gemm2(const float* __restrict__ h, const float* __restrict__ W,
                        __half* __restrict__ out, int N) {
  __shared__ float w[64 * 16];
  for (int i = threadIdx.x; i < 64 * 16; i += 256) w[i] = W[i];
  __syncthreads();
  int t = blockIdx.x * blockDim.x + threadIdx.x;
  int n = t >> 4;
  int j = t & 15;
  if (n >= N) return;
  const float4* hr = (const float4*)(h + (size_t)n * 64);
  float acc = 0.f;
#pragma unroll
  for (int k4 = 0; k4 < 16; ++k4) {
    float4 hv = hr[k4];
    acc = fmaf(hv.x, w[(k4 * 4 + 0) * 16 + j], acc);
    acc = fmaf(hv.y, w[(k4 * 4 + 1) * 16 + j], acc);
    acc = fmaf(hv.z, w[(k4 * 4 + 2) * 16 + j], acc);
    acc = fmaf(hv.w, w[(k4 * 4 + 3) * 16 + j], acc);
  }
  out[(size_t)n * 16 + j] = __float2half(acc);
}

// ---- fused agg layer 2 + bias + log_softmax: block = bucket ----
__global__ void k_agg2(const __half* __restrict__ h2, const float* __restrict__ dis,
                       const int* __restrict__ tmp, const int* __restrict__ bbase,
                       const int* __restrict__ bcnt, const float* __restrict__ b2,
                       float* __restrict__ out, int N) {
  __shared__ float acc[BSH][16];
  int b = blockIdx.x, t = threadIdx.x;
  int lane = t & 63, wv = t >> 6;
  int j = lane & 15, es = lane >> 4;  // 4 edge substreams x 16 features per wave
  for (int idx = t; idx < BSH * 16; idx += 256) {
    int l = idx >> 4, jj = idx & 15;
    int n = b * BSH + l;
    acc[l][jj] = (n < N) ? dis[n] * __half2float(h2[(size_t)n * 16 + jj]) : 0.f;
  }
  __syncthreads();
  int beg = bbase[b], end = beg + bcnt[b];
  // wave wv owns chunks [beg+wv*8, +8) stepping 32; 2x4 edges in flight
  for (int e0 = beg + wv * 8; e0 < end; e0 += 32) {
    int eA = e0 + es;
    int eB = e0 + 4 + es;
    if (eA < end) {
      int p = tmp[eA];
      int s = p >> 7;
      atomicAdd(&acc[p & 127][j], dis[s] * __half2float(h2[(size_t)s * 16 + j]));
    }
    if (eB < end) {
      int p = tmp[eB];
      int s = p >> 7;
      atomicAdd(&acc[p & 127][j], dis[s] * __half2float(h2[(size_t)s * 16 + j]));
    }
  }
  __syncthreads();
  int g = t >> 4, jj = t & 15;
  float bias = b2[jj];
  for (int l = g; l < BSH; l += 16) {
    int n = b * BSH + l;
    if (n >= N) continue;
    float v = fmaf(dis[n], acc[l][jj], bias);
    float m = v;
#pragma unroll
    for (int o = 1; o < 16; o <<= 1) m = fmaxf(m, __shfl_xor(m, o, 16));
    float ex = __expf(v - m);
    float sum = ex;
#pragma unroll
    for (int o = 1; o < 16; o <<= 1) sum += __shfl_xor(sum, o, 16);
    out[(size_t)n * 16 + jj] = (v - m) - __logf(sum);
  }
}

extern "C" void kernel_launch(void* const* d_in, const int* in_sizes, int n_in,
                              void* d_out, int out_size, void* d_ws, size_t ws_size,
                              hipStream_t stream) {
  const float* x = (const float*)d_in[0];
  const int* ei = (const int*)d_in[1];
  const float* W1 = (const float*)d_in[2];
  const float* b1 = (const float*)d_in[3];
  const float* W2 = (const float*)d_in[4];
  const float* b2 = (const float*)d_in[5];
  float* out = (float*)d_out;

  int N = in_sizes[0] / F1;  // 100000
  int E = in_sizes[1] / 2;   // 1600000
  const int* src = ei;
  const int* dst = ei + E;
  int nb = (N + BSH - 1) >> 7;  // 782 buckets

  char* ws = (char*)d_ws;
  size_t o_bcnt  = 0;                                        // MAXB int
  size_t o_bbase = o_bcnt + MAXB * 4;                        // MAXB int
  size_t o_bcur  = o_bbase + MAXB * 4;                       // MAXB int
  size_t o_dis   = o_bcur + MAXB * 4;                        // N f32
  size_t o_tmp   = (o_dis + (size_t)N * 4 + 255) & ~(size_t)255;        // E int
  size_t o_h1    = (o_tmp + (size_t)E * 4 + 255) & ~(size_t)255;        // N*64 fp16
  size_t o_hr    = (o_h1 + (size_t)N * 64 * 2 + 255) & ~(size_t)255;    // N*64 f32
  size_t o_h2    = (o_hr + (size_t)N * 64 * 4 + 255) & ~(size_t)255;    // N*16 fp16

  int* bcnt   = (int*)(ws + o_bcnt);
  int* bbase  = (int*)(ws + o_bbase);
  int* bcur   = (int*)(ws + o_bcur);
  float* dis  = (float*)(ws + o_dis);
  int* tmp    = (int*)(ws + o_tmp);
  __half* h1  = (__half*)(ws + o_h1);
  float* hr   = (float*)(ws + o_hr);
  __half* h2  = (__half*)(ws + o_h2);

  hipMemsetAsync(bcnt, 0, MAXB * 4, stream);

  k_hist<<<256, 256, 0, stream>>>(dst, bcnt, E, nb);
  k_scanB<<<1, MAXB, 0, stream>>>(bcnt, bbase, bcur, nb);
  k_scatter<<<128, 256, 0, stream>>>(src, dst, bcur, tmp, E, nb);
  k_bdis<<<nb, 256, 0, stream>>>(tmp, bbase, bcnt, dis, N);

  k_gemm1<<<2048, 256, 0, stream>>>(x, W1, h1, N);
  k_agg1<<<nb, 256, 0, stream>>>(h1, dis, tmp, bbase, bcnt, b1, hr, N);
  k_gemm2<<<((size_t)N * 16 + 255) / 256, 256, 0, stream>>>(hr, W2, h2, N);
  k_agg2<<<nb, 256, 0, stream>>>(h2, dis, tmp, bbase, bcnt, b2, out, N);
}

// Round 4
// 355.560 us; speedup vs baseline: 3.0987x; 3.0987x over previous
//
#include <hip/hip_runtime.h>
#include <hip/hip_bf16.h>
#include <hip/hip_fp16.h>

// GCN 2-layer: h1 = relu(A_hat (x@W1) + b1); out = log_softmax(A_hat (h1@W2) + b2)
// R4: R2's wave-per-node pull aggregation (the fast structure) + two-level radix
// partition for the CSR build (dense, single-XCD writes; kills k_fill's 17x write
// amplification). Rows pre-scaled by dis at GEMM output so edge loops are a single
// fp16 gather per edge.

#define F1 64
#define F2 16
#define MAXB 1024
#define BSH 128  // nodes per bucket; bucket = dst>>7, local = dst&127

// ---- 1) histogram edges by bucket ----
__global__ void k_hist(const int* __restrict__ dst, int* __restrict__ bcnt,
                       int E, int nb) {
  __shared__ int h[MAXB];
  int t = threadIdx.x;
  for (int i = t; i < MAXB; i += 256) h[i] = 0;
  __syncthreads();
  int chunk = (E + gridDim.x - 1) / gridDim.x;
  int beg = blockIdx.x * chunk;
  int end = min(beg + chunk, E);
  for (int e = beg + t; e < end; e += 256) atomicAdd(&h[dst[e] >> 7], 1);
  __syncthreads();
  for (int i = t; i < nb; i += 256)
    if (h[i]) atomicAdd(&bcnt[i], h[i]);
}

// ---- 2) exclusive scan of bucket counts -> base; init cursor ----
__global__ void k_scanB(const int* __restrict__ bcnt, int* __restrict__ bbase,
                        int* __restrict__ bcur, int nb) {
  __shared__ int lds[MAXB];
  int t = threadIdx.x;  // 1024 threads
  lds[t] = (t < nb) ? bcnt[t] : 0;
  __syncthreads();
  for (int off = 1; off < MAXB; off <<= 1) {
    int add = (t >= off) ? lds[t - off] : 0;
    __syncthreads();
    lds[t] += add;
    __syncthreads();
  }
  if (t < nb) {
    int b = (t == 0) ? 0 : lds[t - 1];
    bbase[t] = b;
    bcur[t] = b;
  }
}

// ---- 3) scatter packed edges into bucket regions ----
__global__ void k_scatter(const int* __restrict__ src, const int* __restrict__ dst,
                          int* __restrict__ bcur, int* __restrict__ tmp,
                          int E, int nb) {
  __shared__ int h[MAXB];
  __shared__ int base[MAXB];
  int t = threadIdx.x;
  for (int i = t; i < MAXB; i += 256) h[i] = 0;
  __syncthreads();
  int chunk = (E + gridDim.x - 1) / gridDim.x;
  int beg = blockIdx.x * chunk;
  int end = min(beg + chunk, E);
  for (int e = beg + t; e < end; e += 256) atomicAdd(&h[dst[e] >> 7], 1);
  __syncthreads();
  for (int i = t; i < nb; i += 256) {
    int c = h[i];
    base[i] = c ? atomicAdd(&bcur[i], c) : 0;
    h[i] = 0;  // reuse as local cursor
  }
  __syncthreads();
  for (int e = beg + t; e < end; e += 256) {
    int d = dst[e];
    int b = d >> 7;
    int off = atomicAdd(&h[b], 1);
    tmp[base[b] + off] = (src[e] << 7) | (d & 127);
  }
}

// ---- 4) per-bucket counting sort -> csr + rowptr + dis (all dense writes) ----
__global__ void k_csr(const int* __restrict__ tmp, const int* __restrict__ bbase,
                      const int* __restrict__ bcnt, int* __restrict__ csr,
                      int* __restrict__ rowptr, float* __restrict__ dis, int N) {
  __shared__ int cnt[BSH];
  __shared__ int sc[BSH];
  __shared__ int lofs[BSH];
  int b = blockIdx.x, t = threadIdx.x;
  if (t < BSH) cnt[t] = 0;
  __syncthreads();
  int beg = bbase[b], end = beg + bcnt[b];
  for (int e = beg + t; e < end; e += 256) atomicAdd(&cnt[tmp[e] & 127], 1);
  __syncthreads();
  if (t < BSH) sc[t] = cnt[t];
  __syncthreads();
  for (int off = 1; off < BSH; off <<= 1) {
    int a = (t < BSH && t >= off) ? sc[t - off] : 0;
    __syncthreads();
    if (t < BSH) sc[t] += a;
    __syncthreads();
  }
  if (t < BSH) {
    int excl = (t == 0) ? 0 : sc[t - 1];
    lofs[t] = excl;
    int n = b * BSH + t;
    if (n <= N) rowptr[n] = beg + excl;  // n==N gets beg+total = E
    if (n < N) dis[n] = rsqrtf((float)(cnt[t] + 1));
    cnt[t] = 0;  // reuse as cursor
  }
  __syncthreads();
  for (int e = beg + t; e < end; e += 256) {
    int p = tmp[e];
    int l = p & 127;
    int off = atomicAdd(&cnt[l], 1);
    csr[beg + lofs[l] + off] = p >> 7;
  }
}

// ---- GEMM1: h1[n] = dis[n] * (x[n] @ W1), fp16 (bias after agg) ----
__global__ void k_gemm1(const float* __restrict__ x, const float* __restrict__ W,
                        const float* __restrict__ dis, __half* __restrict__ out, int N) {
  __shared__ float w[64 * 64];
  for (int i = threadIdx.x; i < 64 * 64; i += 256) w[i] = W[i];
  __syncthreads();
  int lane = threadIdx.x & 63;
  int wv = threadIdx.x >> 6;
  for (int n = blockIdx.x * 4 + wv; n < N; n += gridDim.x * 4) {
    const float4* xr = (const float4*)(x + (size_t)n * 64);
    float acc = 0.f;
#pragma unroll
    for (int k4 = 0; k4 < 16; ++k4) {
      float4 xv = xr[k4];  // wave-uniform broadcast
      acc = fmaf(xv.x, w[(k4 * 4 + 0) * 64 + lane], acc);
      acc = fmaf(xv.y, w[(k4 * 4 + 1) * 64 + lane], acc);
      acc = fmaf(xv.z, w[(k4 * 4 + 2) * 64 + lane], acc);
      acc = fmaf(xv.w, w[(k4 * 4 + 3) * 64 + lane], acc);
    }
    out[(size_t)n * 64 + lane] = __float2half(acc * dis[n]);
  }
}

// ---- agg layer 1: wave/node, lane=feature; single fp16 gather per edge ----
__global__ void k_agg1(const __half* __restrict__ h, const float* __restrict__ dis,
                       const int* __restrict__ rowptr, const int* __restrict__ csr,
                       const float* __restrict__ b1, float* __restrict__ out, int N) {
  int gt = blockIdx.x * blockDim.x + threadIdx.x;
  int n = gt >> 6;
  int lane = gt & 63;
  if (n >= N) return;
  float acc = __half2float(h[(size_t)n * 64 + lane]);  // self loop (g[n]=dis[n]h[n])
  int beg = rowptr[n], end = rowptr[n + 1];
  int e = beg;
  for (; e + 4 <= end; e += 4) {
    int s0 = csr[e], s1 = csr[e + 1], s2 = csr[e + 2], s3 = csr[e + 3];
    float v0 = __half2float(h[(size_t)s0 * 64 + lane]);
    float v1 = __half2float(h[(size_t)s1 * 64 + lane]);
    float v2 = __half2float(h[(size_t)s2 * 64 + lane]);
    float v3 = __half2float(h[(size_t)s3 * 64 + lane]);
    acc += v0 + v1 + v2 + v3;
  }
  for (; e < end; ++e)
    acc += __half2float(h[(size_t)csr[e] * 64 + lane]);
  float v = fmaf(dis[n], acc, b1[lane]);
  out[(size_t)n * 64 + lane] = fmaxf(v, 0.f);
}

// ---- GEMM2: h2[n] = dis[n] * (hr[n] @ W2), fp16 ----
__global__ void k_gemm2(const float* __restrict__ h, const float* __restrict__ W,
                        const float* __restrict__ dis, __half* __restrict__ out, int N) {
  __shared__ float w[64 * 16];
  for (int i = threadIdx.x; i < 64 * 16; i += 256) w[i] = W[i];
  __syncthreads();
  int t = blockIdx.x * blockDim.x + threadIdx.x;
  int n = t >> 4;
  int j = t & 15;
  if (n >= N) return;
  const float4* hr = (const float4*)(h + (size_t)n * 64);
  float acc = 0.f;
#pragma unroll
  for (int k4 = 0; k4 < 16; ++k4) {
    float4 hv = hr[k4];
    acc = fmaf(hv.x, w[(k4 * 4 + 0) * 16 + j], acc);
    acc = fmaf(hv.y, w[(k4 * 4 + 1) * 16 + j], acc);
    acc = fmaf(hv.z, w[(k4 * 4 + 2) * 16 + j], acc);
    acc = fmaf(hv.w, w[(k4 * 4 + 3) * 16 + j], acc);
  }
  out[(size_t)n * 16 + j] = __float2half(acc * dis[n]);
}

// ---- agg layer 2 + bias + log_softmax: wave/node, 4 edge substreams x 16 feats ----
__global__ void k_agg2(const __half* __restrict__ h2, const float* __restrict__ dis,
                       const int* __restrict__ rowptr, const int* __restrict__ csr,
                       const float* __restrict__ b2, float* __restrict__ out, int N) {
  int tid = threadIdx.x;
  int wv = tid >> 6;
  int lane = tid & 63;
  int j = lane & 15;
  int sub = lane >> 4;
  int n = blockIdx.x * 4 + wv;
  if (n >= N) return;
  float acc = (sub == 0) ? __half2float(h2[(size_t)n * 16 + j]) : 0.f;  // self loop
  int beg = rowptr[n], end = rowptr[n + 1];
  for (int e = beg + sub; e < end; e += 4)
    acc += __half2float(h2[(size_t)csr[e] * 16 + j]);
  acc += __shfl_xor(acc, 16);
  acc += __shfl_xor(acc, 32);
  float v = fmaf(dis[n], acc, b2[j]);
  float m = v;
#pragma unroll
  for (int o = 1; o < 16; o <<= 1) m = fmaxf(m, __shfl_xor(m, o, 16));
  float ex = __expf(v - m);
  float sum = ex;
#pragma unroll
  for (int o = 1; o < 16; o <<= 1) sum += __shfl_xor(sum, o, 16);
  if (sub == 0) out[(size_t)n * 16 + j] = (v - m) - __logf(sum);
}

extern "C" void kernel_launch(void* const* d_in, const int* in_sizes, int n_in,
                              void* d_out, int out_size, void* d_ws, size_t ws_size,
                              hipStream_t stream) {
  const float* x = (const float*)d_in[0];
  const int* ei = (const int*)d_in[1];
  const float* W1 = (const float*)d_in[2];
  const float* b1 = (const float*)d_in[3];
  const float* W2 = (const float*)d_in[4];
  const float* b2 = (const float*)d_in[5];
  float* out = (float*)d_out;

  int N = in_sizes[0] / F1;  // 100000
  int E = in_sizes[1] / 2;   // 1600000
  const int* src = ei;
  const int* dst = ei + E;
  int nb = (N + BSH - 1) >> 7;  // 782 buckets

  char* ws = (char*)d_ws;
  size_t o_bcnt  = 0;                                        // MAXB int
  size_t o_bbase = o_bcnt + MAXB * 4;                        // MAXB int
  size_t o_bcur  = o_bbase + MAXB * 4;                       // MAXB int
  size_t o_dis   = o_bcur + MAXB * 4;                        // N f32
  size_t o_rowp  = (o_dis + (size_t)N * 4 + 255) & ~(size_t)255;        // N+1 int
  size_t o_tmp   = (o_rowp + (size_t)(N + 1) * 4 + 255) & ~(size_t)255; // E int
  size_t o_csr   = (o_tmp + (size_t)E * 4 + 255) & ~(size_t)255;        // E int
  size_t o_h1    = (o_csr + (size_t)E * 4 + 255) & ~(size_t)255;        // N*64 fp16
  size_t o_hr    = (o_h1 + (size_t)N * 64 * 2 + 255) & ~(size_t)255;    // N*64 f32
  size_t o_h2    = (o_hr + (size_t)N * 64 * 4 + 255) & ~(size_t)255;    // N*16 fp16

  int* bcnt   = (int*)(ws + o_bcnt);
  int* bbase  = (int*)(ws + o_bbase);
  int* bcur   = (int*)(ws + o_bcur);
  float* dis  = (float*)(ws + o_dis);
  int* rowptr = (int*)(ws + o_rowp);
  int* tmp    = (int*)(ws + o_tmp);
  int* csr    = (int*)(ws + o_csr);
  __half* h1  = (__half*)(ws + o_h1);
  float* hr   = (float*)(ws + o_hr);
  __half* h2  = (__half*)(ws + o_h2);

  hipMemsetAsync(bcnt, 0, MAXB * 4, stream);

  k_hist<<<256, 256, 0, stream>>>(dst, bcnt, E, nb);
  k_scanB<<<1, MAXB, 0, stream>>>(bcnt, bbase, bcur, nb);
  k_scatter<<<128, 256, 0, stream>>>(src, dst, bcur, tmp, E, nb);
  k_csr<<<nb, 256, 0, stream>>>(tmp, bbase, bcnt, csr, rowptr, dis, N);

  k_gemm1<<<2048, 256, 0, stream>>>(x, W1, dis, h1, N);
  k_agg1<<<((size_t)N * 64 + 255) / 256, 256, 0, stream>>>(h1, dis, rowptr, csr, b1, hr, N);
  k_gemm2<<<((size_t)N * 16 + 255) / 256, 256, 0, stream>>>(hr, W2, dis, h2, N);
  k_agg2<<<(N + 3) / 4, 256, 0, stream>>>(h2, dis, rowptr, csr, b2, out, N);
}

// Round 5
// 282.905 us; speedup vs baseline: 3.8946x; 1.2568x over previous
//
#include <hip/hip_runtime.h>
#include <hip/hip_bf16.h>
#include <hip/hip_fp16.h>

// GCN 2-layer: h1 = relu(A_hat (x@W1) + b1); out = log_softmax(A_hat (h1@W2) + b2)
// R5: MFMA GEMMs (fp16 in, fp32 acc), two-level radix partition CSR build (R4),
// wave-per-node pull aggregation with fp16 gather tables pre-scaled by dis.

#define F1 64
#define F2 16
#define MAXB 1024
#define BSH 128  // nodes per bucket; bucket = dst>>7, local = dst&127

typedef _Float16 f16x8 __attribute__((ext_vector_type(8)));
typedef float f32x4 __attribute__((ext_vector_type(4)));

// ---- 1) histogram edges by bucket ----
__global__ void k_hist(const int* __restrict__ dst, int* __restrict__ bcnt,
                       int E, int nb) {
  __shared__ int h[MAXB];
  int t = threadIdx.x;
  for (int i = t; i < MAXB; i += 256) h[i] = 0;
  __syncthreads();
  int chunk = (E + gridDim.x - 1) / gridDim.x;
  int beg = blockIdx.x * chunk;
  int end = min(beg + chunk, E);
  for (int e = beg + t; e < end; e += 256) atomicAdd(&h[dst[e] >> 7], 1);
  __syncthreads();
  for (int i = t; i < nb; i += 256)
    if (h[i]) atomicAdd(&bcnt[i], h[i]);
}

// ---- 2) exclusive scan of bucket counts -> base; init cursor ----
__global__ void k_scanB(const int* __restrict__ bcnt, int* __restrict__ bbase,
                        int* __restrict__ bcur, int nb) {
  __shared__ int lds[MAXB];
  int t = threadIdx.x;  // 1024 threads
  lds[t] = (t < nb) ? bcnt[t] : 0;
  __syncthreads();
  for (int off = 1; off < MAXB; off <<= 1) {
    int add = (t >= off) ? lds[t - off] : 0;
    __syncthreads();
    lds[t] += add;
    __syncthreads();
  }
  if (t < nb) {
    int b = (t == 0) ? 0 : lds[t - 1];
    bbase[t] = b;
    bcur[t] = b;
  }
}

// ---- 3) scatter packed edges into bucket regions ----
__global__ void k_scatter(const int* __restrict__ src, const int* __restrict__ dst,
                          int* __restrict__ bcur, int* __restrict__ tmp,
                          int E, int nb) {
  __shared__ int h[MAXB];
  __shared__ int base[MAXB];
  int t = threadIdx.x;
  for (int i = t; i < MAXB; i += 256) h[i] = 0;
  __syncthreads();
  int chunk = (E + gridDim.x - 1) / gridDim.x;
  int beg = blockIdx.x * chunk;
  int end = min(beg + chunk, E);
  for (int e = beg + t; e < end; e += 256) atomicAdd(&h[dst[e] >> 7], 1);
  __syncthreads();
  for (int i = t; i < nb; i += 256) {
    int c = h[i];
    base[i] = c ? atomicAdd(&bcur[i], c) : 0;
    h[i] = 0;  // reuse as local cursor
  }
  __syncthreads();
  for (int e = beg + t; e < end; e += 256) {
    int d = dst[e];
    int b = d >> 7;
    int off = atomicAdd(&h[b], 1);
    tmp[base[b] + off] = (src[e] << 7) | (d & 127);
  }
}

// ---- 4) per-bucket counting sort -> csr + rowptr + dis (dense writes) ----
__global__ void k_csr(const int* __restrict__ tmp, const int* __restrict__ bbase,
                      const int* __restrict__ bcnt, int* __restrict__ csr,
                      int* __restrict__ rowptr, float* __restrict__ dis, int N) {
  __shared__ int cnt[BSH];
  __shared__ int sc[BSH];
  __shared__ int lofs[BSH];
  int b = blockIdx.x, t = threadIdx.x;
  if (t < BSH) cnt[t] = 0;
  __syncthreads();
  int beg = bbase[b], end = beg + bcnt[b];
  for (int e = beg + t; e < end; e += 256) atomicAdd(&cnt[tmp[e] & 127], 1);
  __syncthreads();
  if (t < BSH) sc[t] = cnt[t];
  __syncthreads();
  for (int off = 1; off < BSH; off <<= 1) {
    int a = (t < BSH && t >= off) ? sc[t - off] : 0;
    __syncthreads();
    if (t < BSH) sc[t] += a;
    __syncthreads();
  }
  if (t < BSH) {
    int excl = (t == 0) ? 0 : sc[t - 1];
    lofs[t] = excl;
    int n = b * BSH + t;
    if (n <= N) rowptr[n] = beg + excl;  // n==N gets E
    if (n < N) dis[n] = rsqrtf((float)(cnt[t] + 1));
    cnt[t] = 0;  // reuse as cursor
  }
  __syncthreads();
  for (int e = beg + t; e < end; e += 256) {
    int p = tmp[e];
    int l = p & 127;
    int off = atomicAdd(&cnt[l], 1);
    csr[beg + lofs[l] + off] = p >> 7;
  }
}

// ---- prep: transpose weights to fp16 WT[n][k] (B-operand friendly) ----
__global__ void k_prepW(const float* __restrict__ W1, const float* __restrict__ W2,
                        __half* __restrict__ W1T, __half* __restrict__ W2T) {
  int t = threadIdx.x;
  for (int i = t; i < 64 * 64; i += 256) {
    int n = i >> 6, k = i & 63;
    W1T[i] = __float2half(W1[k * 64 + n]);
  }
  for (int i = t; i < 16 * 64; i += 256) {
    int n = i >> 6, k = i & 63;
    W2T[i] = __float2half(W2[k * 16 + n]);
  }
}

// ---- GEMM1 (MFMA): h1[n] = fp16(dis[n] * (x[n] @ W1)); 64 rows/block ----
__global__ void k_gemm1(const float* __restrict__ x, const __half* __restrict__ W1T,
                        const float* __restrict__ dis, __half* __restrict__ out, int N) {
  __shared__ _Float16 wt[64 * 72];  // WT padded: stride 72 halves (bank-safe b128)
  int t = threadIdx.x;
  for (int i = t; i < 64 * 64; i += 256) {
    int n = i >> 6, k = i & 63;
    wt[n * 72 + k] = ((const _Float16*)W1T)[i];
  }
  __syncthreads();
  int wv = t >> 6, lane = t & 63;
  int m = lane & 15, q = lane >> 4;  // quad
  int row0 = blockIdx.x * 64 + wv * 16;
  int arow = min(row0 + m, N - 1);  // clamp for load safety
  // A fragments: x[arow][kt*32 + q*8 + j], fp32 -> fp16
  f16x8 a[2];
#pragma unroll
  for (int kt = 0; kt < 2; ++kt) {
    const float4* xp = (const float4*)(x + (size_t)arow * 64 + kt * 32 + q * 8);
    float4 u = xp[0], v = xp[1];
    a[kt][0] = (_Float16)u.x; a[kt][1] = (_Float16)u.y;
    a[kt][2] = (_Float16)u.z; a[kt][3] = (_Float16)u.w;
    a[kt][4] = (_Float16)v.x; a[kt][5] = (_Float16)v.y;
    a[kt][6] = (_Float16)v.z; a[kt][7] = (_Float16)v.w;
  }
  f32x4 acc[4] = {};
#pragma unroll
  for (int kt = 0; kt < 2; ++kt) {
#pragma unroll
    for (int c = 0; c < 4; ++c) {
      f16x8 bfrag = *(const f16x8*)&wt[(c * 16 + m) * 72 + kt * 32 + q * 8];
      acc[c] = __builtin_amdgcn_mfma_f32_16x16x32_f16(a[kt], bfrag, acc[c], 0, 0, 0);
    }
  }
  // epilogue: C/D row=(q*4+reg), col=c*16+m
  float dn[4];
#pragma unroll
  for (int r = 0; r < 4; ++r) {
    int n = row0 + q * 4 + r;
    dn[r] = (n < N) ? dis[n] : 0.f;
  }
#pragma unroll
  for (int r = 0; r < 4; ++r) {
    int n = row0 + q * 4 + r;
    if (n < N) {
#pragma unroll
      for (int c = 0; c < 4; ++c)
        out[(size_t)n * 64 + c * 16 + m] = __float2half(acc[c][r] * dn[r]);
    }
  }
}

// ---- agg layer 1: wave/node, lane=feature; fp16 gather, fp16 relu out ----
__global__ void k_agg1(const __half* __restrict__ h, const float* __restrict__ dis,
                       const int* __restrict__ rowptr, const int* __restrict__ csr,
                       const float* __restrict__ b1, __half* __restrict__ out, int N) {
  int gt = blockIdx.x * blockDim.x + threadIdx.x;
  int n = gt >> 6;
  int lane = gt & 63;
  if (n >= N) return;
  float acc = __half2float(h[(size_t)n * 64 + lane]);  // self loop (pre-scaled)
  int beg = rowptr[n], end = rowptr[n + 1];
  int e = beg;
  for (; e + 4 <= end; e += 4) {
    int s0 = csr[e], s1 = csr[e + 1], s2 = csr[e + 2], s3 = csr[e + 3];
    float v0 = __half2float(h[(size_t)s0 * 64 + lane]);
    float v1 = __half2float(h[(size_t)s1 * 64 + lane]);
    float v2 = __half2float(h[(size_t)s2 * 64 + lane]);
    float v3 = __half2float(h[(size_t)s3 * 64 + lane]);
    acc += v0 + v1 + v2 + v3;
  }
  for (; e < end; ++e)
    acc += __half2float(h[(size_t)csr[e] * 64 + lane]);
  float v = fmaf(dis[n], acc, b1[lane]);
  out[(size_t)n * 64 + lane] = __float2half(fmaxf(v, 0.f));
}

// ---- GEMM2 (MFMA): h2[n] = fp16(dis[n] * (hr[n] @ W2)); 64 rows/block ----
__global__ void k_gemm2(const __half* __restrict__ hr, const __half* __restrict__ W2T,
                        const float* __restrict__ dis, __half* __restrict__ out, int N) {
  __shared__ _Float16 wt[16 * 72];
  int t = threadIdx.x;
  for (int i = t; i < 16 * 64; i += 256) {
    int n = i >> 6, k = i & 63;
    wt[n * 72 + k] = ((const _Float16*)W2T)[i];
  }
  __syncthreads();
  int wv = t >> 6, lane = t & 63;
  int m = lane & 15, q = lane >> 4;
  int row0 = blockIdx.x * 64 + wv * 16;
  int arow = min(row0 + m, N - 1);
  f32x4 acc = {};
#pragma unroll
  for (int kt = 0; kt < 2; ++kt) {
    f16x8 a = *(const f16x8*)((const _Float16*)hr + (size_t)arow * 64 + kt * 32 + q * 8);
    f16x8 bfrag = *(const f16x8*)&wt[m * 72 + kt * 32 + q * 8];
    acc = __builtin_amdgcn_mfma_f32_16x16x32_f16(a, bfrag, acc, 0, 0, 0);
  }
#pragma unroll
  for (int r = 0; r < 4; ++r) {
    int n = row0 + q * 4 + r;
    if (n < N)
      out[(size_t)n * 16 + m] = __float2half(acc[r] * dis[n]);
  }
}

// ---- agg layer 2 + bias + log_softmax: wave/node, 4 substreams x 16 feats ----
__global__ void k_agg2(const __half* __restrict__ h2, const float* __restrict__ dis,
                       const int* __restrict__ rowptr, const int* __restrict__ csr,
                       const float* __restrict__ b2, float* __restrict__ out, int N) {
  int tid = threadIdx.x;
  int wv = tid >> 6;
  int lane = tid & 63;
  int j = lane & 15;
  int sub = lane >> 4;
  int n = blockIdx.x * 4 + wv;
  if (n >= N) return;
  float acc = (sub == 0) ? __half2float(h2[(size_t)n * 16 + j]) : 0.f;  // self loop
  int beg = rowptr[n], end = rowptr[n + 1];
  for (int e = beg + sub; e < end; e += 4)
    acc += __half2float(h2[(size_t)csr[e] * 16 + j]);
  acc += __shfl_xor(acc, 16);
  acc += __shfl_xor(acc, 32);
  float v = fmaf(dis[n], acc, b2[j]);
  float m = v;
#pragma unroll
  for (int o = 1; o < 16; o <<= 1) m = fmaxf(m, __shfl_xor(m, o, 16));
  float ex = __expf(v - m);
  float sum = ex;
#pragma unroll
  for (int o = 1; o < 16; o <<= 1) sum += __shfl_xor(sum, o, 16);
  if (sub == 0) out[(size_t)n * 16 + j] = (v - m) - __logf(sum);
}

extern "C" void kernel_launch(void* const* d_in, const int* in_sizes, int n_in,
                              void* d_out, int out_size, void* d_ws, size_t ws_size,
                              hipStream_t stream) {
  const float* x = (const float*)d_in[0];
  const int* ei = (const int*)d_in[1];
  const float* W1 = (const float*)d_in[2];
  const float* b1 = (const float*)d_in[3];
  const float* W2 = (const float*)d_in[4];
  const float* b2 = (const float*)d_in[5];
  float* out = (float*)d_out;

  int N = in_sizes[0] / F1;  // 100000
  int E = in_sizes[1] / 2;   // 1600000
  const int* src = ei;
  const int* dst = ei + E;
  int nb = (N + BSH - 1) >> 7;  // 782 buckets

  char* ws = (char*)d_ws;
  size_t o_bcnt  = 0;                                        // MAXB int
  size_t o_bbase = o_bcnt + MAXB * 4;
  size_t o_bcur  = o_bbase + MAXB * 4;
  size_t o_w1t   = o_bcur + MAXB * 4;                        // 64*64 fp16
  size_t o_w2t   = o_w1t + 64 * 64 * 2;                      // 16*64 fp16
  size_t o_dis   = (o_w2t + 16 * 64 * 2 + 255) & ~(size_t)255;          // N f32
  size_t o_rowp  = (o_dis + (size_t)N * 4 + 255) & ~(size_t)255;        // N+1 int
  size_t o_tmp   = (o_rowp + (size_t)(N + 1) * 4 + 255) & ~(size_t)255; // E int
  size_t o_csr   = (o_tmp + (size_t)E * 4 + 255) & ~(size_t)255;        // E int
  size_t o_h1    = (o_csr + (size_t)E * 4 + 255) & ~(size_t)255;        // N*64 fp16
  size_t o_hr    = (o_h1 + (size_t)N * 64 * 2 + 255) & ~(size_t)255;    // N*64 fp16
  size_t o_h2    = (o_hr + (size_t)N * 64 * 2 + 255) & ~(size_t)255;    // N*16 fp16

  int* bcnt    = (int*)(ws + o_bcnt);
  int* bbase   = (int*)(ws + o_bbase);
  int* bcur    = (int*)(ws + o_bcur);
  __half* W1T  = (__half*)(ws + o_w1t);
  __half* W2T  = (__half*)(ws + o_w2t);
  float* dis   = (float*)(ws + o_dis);
  int* rowptr  = (int*)(ws + o_rowp);
  int* tmp     = (int*)(ws + o_tmp);
  int* csr     = (int*)(ws + o_csr);
  __half* h1   = (__half*)(ws + o_h1);
  __half* hr   = (__half*)(ws + o_hr);
  __half* h2   = (__half*)(ws + o_h2);

  hipMemsetAsync(bcnt, 0, MAXB * 4, stream);

  k_hist<<<256, 256, 0, stream>>>(dst, bcnt, E, nb);
  k_scanB<<<1, MAXB, 0, stream>>>(bcnt, bbase, bcur, nb);
  k_scatter<<<128, 256, 0, stream>>>(src, dst, bcur, tmp, E, nb);
  k_csr<<<nb, 256, 0, stream>>>(tmp, bbase, bcnt, csr, rowptr, dis, N);
  k_prepW<<<1, 256, 0, stream>>>(W1, W2, W1T, W2T);

  int gb = (N + 63) / 64;  // 1563
  k_gemm1<<<gb, 256, 0, stream>>>(x, W1T, dis, h1, N);
  k_agg1<<<((size_t)N * 64 + 255) / 256, 256, 0, stream>>>(h1, dis, rowptr, csr, b1, hr, N);
  k_gemm2<<<gb, 256, 0, stream>>>(hr, W2T, dis, h2, N);
  k_agg2<<<(N + 3) / 4, 256, 0, stream>>>(h2, dis, rowptr, csr, b2, out, N);
}

// Round 6
// 249.530 us; speedup vs baseline: 4.4154x; 1.1337x over previous
//
#include <hip/hip_runtime.h>
#include <hip/hip_bf16.h>
#include <hip/hip_fp16.h>

// GCN 2-layer: h1 = relu(A_hat (x@W1) + b1); out = log_softmax(A_hat (h1@W2) + b2)
// R6: agg kernels restructured: multi-substream wide fp16 gathers (16B/lane),
// packed-fp16 accumulate, shfl cross-substream reduce. MFMA GEMMs with
// register-resident B fragments (no LDS). Radix-partition CSR build (R4).

#define F1 64
#define F2 16
#define MAXB 1024
#define BSH 128  // nodes per bucket; bucket = dst>>7, local = dst&127

typedef _Float16 f16x8 __attribute__((ext_vector_type(8)));
typedef _Float16 f16x4 __attribute__((ext_vector_type(4)));
typedef float f32x4 __attribute__((ext_vector_type(4)));

__device__ inline f16x8 shfl_xor_f16x8(f16x8 v, int off) {
  union U { f16x8 h; int i[4]; } a, b;
  a.h = v;
#pragma unroll
  for (int k = 0; k < 4; ++k) b.i[k] = __shfl_xor(a.i[k], off);
  return b.h;
}
__device__ inline f16x4 shfl_xor_f16x4(f16x4 v, int off) {
  union U { f16x4 h; int i[2]; } a, b;
  a.h = v;
#pragma unroll
  for (int k = 0; k < 2; ++k) b.i[k] = __shfl_xor(a.i[k], off);
  return b.h;
}

// ---- 1) histogram edges by bucket ----
__global__ void k_hist(const int* __restrict__ dst, int* __restrict__ bcnt,
                       int E, int nb) {
  __shared__ int h[MAXB];
  int t = threadIdx.x;
  for (int i = t; i < MAXB; i += 256) h[i] = 0;
  __syncthreads();
  int chunk = (E + gridDim.x - 1) / gridDim.x;
  int beg = blockIdx.x * chunk;
  int end = min(beg + chunk, E);
  for (int e = beg + t; e < end; e += 256) atomicAdd(&h[dst[e] >> 7], 1);
  __syncthreads();
  for (int i = t; i < nb; i += 256)
    if (h[i]) atomicAdd(&bcnt[i], h[i]);
}

// ---- 2) exclusive scan of bucket counts -> base; init cursor ----
__global__ void k_scanB(const int* __restrict__ bcnt, int* __restrict__ bbase,
                        int* __restrict__ bcur, int nb) {
  __shared__ int lds[MAXB];
  int t = threadIdx.x;  // 1024 threads
  lds[t] = (t < nb) ? bcnt[t] : 0;
  __syncthreads();
  for (int off = 1; off < MAXB; off <<= 1) {
    int add = (t >= off) ? lds[t - off] : 0;
    __syncthreads();
    lds[t] += add;
    __syncthreads();
  }
  if (t < nb) {
    int b = (t == 0) ? 0 : lds[t - 1];
    bbase[t] = b;
    bcur[t] = b;
  }
}

// ---- 3) scatter packed edges into bucket regions ----
__global__ void k_scatter(const int* __restrict__ src, const int* __restrict__ dst,
                          int* __restrict__ bcur, int* __restrict__ tmp,
                          int E, int nb) {
  __shared__ int h[MAXB];
  __shared__ int base[MAXB];
  int t = threadIdx.x;
  for (int i = t; i < MAXB; i += 256) h[i] = 0;
  __syncthreads();
  int chunk = (E + gridDim.x - 1) / gridDim.x;
  int beg = blockIdx.x * chunk;
  int end = min(beg + chunk, E);
  for (int e = beg + t; e < end; e += 256) atomicAdd(&h[dst[e] >> 7], 1);
  __syncthreads();
  for (int i = t; i < nb; i += 256) {
    int c = h[i];
    base[i] = c ? atomicAdd(&bcur[i], c) : 0;
    h[i] = 0;  // reuse as local cursor
  }
  __syncthreads();
  for (int e = beg + t; e < end; e += 256) {
    int d = dst[e];
    int b = d >> 7;
    int off = atomicAdd(&h[b], 1);
    tmp[base[b] + off] = (src[e] << 7) | (d & 127);
  }
}

// ---- 4) per-bucket counting sort -> csr + rowptr + dis (dense writes) ----
__global__ void k_csr(const int* __restrict__ tmp, const int* __restrict__ bbase,
                      const int* __restrict__ bcnt, int* __restrict__ csr,
                      int* __restrict__ rowptr, float* __restrict__ dis, int N) {
  __shared__ int cnt[BSH];
  __shared__ int sc[BSH];
  __shared__ int lofs[BSH];
  int b = blockIdx.x, t = threadIdx.x;
  if (t < BSH) cnt[t] = 0;
  __syncthreads();
  int beg = bbase[b], end = beg + bcnt[b];
  for (int e = beg + t; e < end; e += 256) atomicAdd(&cnt[tmp[e] & 127], 1);
  __syncthreads();
  if (t < BSH) sc[t] = cnt[t];
  __syncthreads();
  for (int off = 1; off < BSH; off <<= 1) {
    int a = (t < BSH && t >= off) ? sc[t - off] : 0;
    __syncthreads();
    if (t < BSH) sc[t] += a;
    __syncthreads();
  }
  if (t < BSH) {
    int excl = (t == 0) ? 0 : sc[t - 1];
    lofs[t] = excl;
    int n = b * BSH + t;
    if (n <= N) rowptr[n] = beg + excl;  // n==N gets E
    if (n < N) dis[n] = rsqrtf((float)(cnt[t] + 1));
    cnt[t] = 0;  // reuse as cursor
  }
  __syncthreads();
  for (int e = beg + t; e < end; e += 256) {
    int p = tmp[e];
    int l = p & 127;
    int off = atomicAdd(&cnt[l], 1);
    csr[beg + lofs[l] + off] = p >> 7;
  }
}

// ---- prep: transpose weights to fp16 WT[n][k] ----
__global__ void k_prepW(const float* __restrict__ W1, const float* __restrict__ W2,
                        __half* __restrict__ W1T, __half* __restrict__ W2T) {
  int t = threadIdx.x;
  for (int i = t; i < 64 * 64; i += 256) {
    int n = i >> 6, k = i & 63;
    W1T[i] = __float2half(W1[k * 64 + n]);
  }
  for (int i = t; i < 16 * 64; i += 256) {
    int n = i >> 6, k = i & 63;
    W2T[i] = __float2half(W2[k * 16 + n]);
  }
}

// ---- GEMM1 (MFMA): h1[n] = fp16(dis[n] * (x[n] @ W1)); 64 rows/block ----
__global__ void k_gemm1(const float* __restrict__ x, const __half* __restrict__ W1T,
                        const float* __restrict__ dis, __half* __restrict__ out, int N) {
  int t = threadIdx.x;
  int wv = t >> 6, lane = t & 63;
  int m = lane & 15, q = lane >> 4;  // quad
  int row0 = blockIdx.x * 64 + wv * 16;
  int arow = min(row0 + m, N - 1);  // clamp for load safety
  // B fragments straight from global (8 KB table, L2-resident)
  const _Float16* wt = (const _Float16*)W1T;
  f16x8 bf[4][2];
#pragma unroll
  for (int c = 0; c < 4; ++c)
#pragma unroll
    for (int kt = 0; kt < 2; ++kt)
      bf[c][kt] = *(const f16x8*)&wt[(c * 16 + m) * 64 + kt * 32 + q * 8];
  // A fragments: x[arow][kt*32 + q*8 + j], fp32 -> fp16
  f16x8 a[2];
#pragma unroll
  for (int kt = 0; kt < 2; ++kt) {
    const float4* xp = (const float4*)(x + (size_t)arow * 64 + kt * 32 + q * 8);
    float4 u = xp[0], v = xp[1];
    a[kt][0] = (_Float16)u.x; a[kt][1] = (_Float16)u.y;
    a[kt][2] = (_Float16)u.z; a[kt][3] = (_Float16)u.w;
    a[kt][4] = (_Float16)v.x; a[kt][5] = (_Float16)v.y;
    a[kt][6] = (_Float16)v.z; a[kt][7] = (_Float16)v.w;
  }
  f32x4 acc[4] = {};
#pragma unroll
  for (int kt = 0; kt < 2; ++kt)
#pragma unroll
    for (int c = 0; c < 4; ++c)
      acc[c] = __builtin_amdgcn_mfma_f32_16x16x32_f16(a[kt], bf[c][kt], acc[c], 0, 0, 0);
  // epilogue: C/D row=(q*4+reg), col=c*16+m
#pragma unroll
  for (int r = 0; r < 4; ++r) {
    int n = row0 + q * 4 + r;
    if (n < N) {
      float dn = dis[n];
#pragma unroll
      for (int c = 0; c < 4; ++c)
        out[(size_t)n * 64 + c * 16 + m] = __float2half(acc[c][r] * dn);
    }
  }
}

// ---- agg layer 1: wave/node; 8 substreams x 8 lanes x 16B gathers ----
__global__ void k_agg1(const __half* __restrict__ h, const float* __restrict__ dis,
                       const int* __restrict__ rowptr, const int* __restrict__ csr,
                       const float* __restrict__ b1, __half* __restrict__ out, int N) {
  int gt = blockIdx.x * blockDim.x + threadIdx.x;
  int n = gt >> 6;
  if (n >= N) return;
  int lane = gt & 63;
  int fl = lane & 7;    // feature-octet lane
  int sub = lane >> 3;  // edge substream
  const _Float16* hp = (const _Float16*)h;
  f16x8 acc = {};
  if (sub == 0)  // self loop (rows pre-scaled by dis)
    acc = *(const f16x8*)&hp[(size_t)n * 64 + fl * 8];
  int beg = rowptr[n], end = rowptr[n + 1];
  for (int e = beg + sub; e < end; e += 8) {
    int s = csr[e];  // 8 consecutive dwords per wave-iter, broadcast in sub
    f16x8 v = *(const f16x8*)&hp[(size_t)s * 64 + fl * 8];
    acc += v;  // v_pk_add_f16 x4
  }
  // reduce across 8 substreams
  acc += shfl_xor_f16x8(acc, 8);
  acc += shfl_xor_f16x8(acc, 16);
  acc += shfl_xor_f16x8(acc, 32);
  if (sub == 0) {
    float dn = dis[n];
    float4 bu = *(const float4*)(b1 + fl * 8);
    float4 bv = *(const float4*)(b1 + fl * 8 + 4);
    float bb[8] = {bu.x, bu.y, bu.z, bu.w, bv.x, bv.y, bv.z, bv.w};
    f16x8 o;
#pragma unroll
    for (int k = 0; k < 8; ++k) {
      float v = fmaf(dn, (float)acc[k], bb[k]);
      o[k] = (_Float16)fmaxf(v, 0.f);
    }
    *(f16x8*)((_Float16*)out + (size_t)n * 64 + fl * 8) = o;
  }
}

// ---- GEMM2 (MFMA): h2[n] = fp16(dis[n] * (hr[n] @ W2)); 64 rows/block ----
__global__ void k_gemm2(const __half* __restrict__ hr, const __half* __restrict__ W2T,
                        const float* __restrict__ dis, __half* __restrict__ out, int N) {
  int t = threadIdx.x;
  int wv = t >> 6, lane = t & 63;
  int m = lane & 15, q = lane >> 4;
  int row0 = blockIdx.x * 64 + wv * 16;
  int arow = min(row0 + m, N - 1);
  const _Float16* wt = (const _Float16*)W2T;
  f32x4 acc = {};
#pragma unroll
  for (int kt = 0; kt < 2; ++kt) {
    f16x8 a = *(const f16x8*)((const _Float16*)hr + (size_t)arow * 64 + kt * 32 + q * 8);
    f16x8 bfrag = *(const f16x8*)&wt[m * 64 + kt * 32 + q * 8];
    acc = __builtin_amdgcn_mfma_f32_16x16x32_f16(a, bfrag, acc, 0, 0, 0);
  }
#pragma unroll
  for (int r = 0; r < 4; ++r) {
    int n = row0 + q * 4 + r;
    if (n < N)
      out[(size_t)n * 16 + m] = __float2half(acc[r] * dis[n]);
  }
}

// ---- agg layer 2 + bias + log_softmax: wave/node; 16 subs x 4 lanes x 8B ----
__global__ void k_agg2(const __half* __restrict__ h2, const float* __restrict__ dis,
                       const int* __restrict__ rowptr, const int* __restrict__ csr,
                       const float* __restrict__ b2, float* __restrict__ out, int N) {
  int gt = blockIdx.x * blockDim.x + threadIdx.x;
  int n = gt >> 6;
  if (n >= N) return;
  int lane = gt & 63;
  int fl = lane & 3;    // feature-quad lane
  int sub = lane >> 2;  // 16 edge substreams
  const _Float16* hp = (const _Float16*)h2;
  f16x4 acc = {};
  if (sub == 0)  // self loop
    acc = *(const f16x4*)&hp[(size_t)n * 16 + fl * 4];
  int beg = rowptr[n], end = rowptr[n + 1];
  for (int e = beg + sub; e < end; e += 16) {
    int s = csr[e];
    f16x4 v = *(const f16x4*)&hp[(size_t)s * 16 + fl * 4];
    acc += v;
  }
  acc += shfl_xor_f16x4(acc, 4);
  acc += shfl_xor_f16x4(acc, 8);
  acc += shfl_xor_f16x4(acc, 16);
  acc += shfl_xor_f16x4(acc, 32);
  if (sub == 0) {
    float dn = dis[n];
    float4 bb = *(const float4*)(b2 + fl * 4);
    float v0 = fmaf(dn, (float)acc[0], bb.x);
    float v1 = fmaf(dn, (float)acc[1], bb.y);
    float v2 = fmaf(dn, (float)acc[2], bb.z);
    float v3 = fmaf(dn, (float)acc[3], bb.w);
    float m = fmaxf(fmaxf(v0, v1), fmaxf(v2, v3));
    m = fmaxf(m, __shfl_xor(m, 1));
    m = fmaxf(m, __shfl_xor(m, 2));
    float s = __expf(v0 - m) + __expf(v1 - m) + __expf(v2 - m) + __expf(v3 - m);
    s += __shfl_xor(s, 1);
    s += __shfl_xor(s, 2);
    float ls = m + __logf(s);
    float4 o = {v0 - ls, v1 - ls, v2 - ls, v3 - ls};
    *(float4*)(out + (size_t)n * 16 + fl * 4) = o;
  }
}

extern "C" void kernel_launch(void* const* d_in, const int* in_sizes, int n_in,
                              void* d_out, int out_size, void* d_ws, size_t ws_size,
                              hipStream_t stream) {
  const float* x = (const float*)d_in[0];
  const int* ei = (const int*)d_in[1];
  const float* W1 = (const float*)d_in[2];
  const float* b1 = (const float*)d_in[3];
  const float* W2 = (const float*)d_in[4];
  const float* b2 = (const float*)d_in[5];
  float* out = (float*)d_out;

  int N = in_sizes[0] / F1;  // 100000
  int E = in_sizes[1] / 2;   // 1600000
  const int* src = ei;
  const int* dst = ei + E;
  int nb = (N + BSH - 1) >> 7;  // 782 buckets

  char* ws = (char*)d_ws;
  size_t o_bcnt  = 0;                                        // MAXB int
  size_t o_bbase = o_bcnt + MAXB * 4;
  size_t o_bcur  = o_bbase + MAXB * 4;
  size_t o_w1t   = o_bcur + MAXB * 4;                        // 64*64 fp16
  size_t o_w2t   = o_w1t + 64 * 64 * 2;                      // 16*64 fp16
  size_t o_dis   = (o_w2t + 16 * 64 * 2 + 255) & ~(size_t)255;          // N f32
  size_t o_rowp  = (o_dis + (size_t)N * 4 + 255) & ~(size_t)255;        // N+1 int
  size_t o_tmp   = (o_rowp + (size_t)(N + 1) * 4 + 255) & ~(size_t)255; // E int
  size_t o_csr   = (o_tmp + (size_t)E * 4 + 255) & ~(size_t)255;        // E int
  size_t o_h1    = (o_csr + (size_t)E * 4 + 255) & ~(size_t)255;        // N*64 fp16
  size_t o_hr    = (o_h1 + (size_t)N * 64 * 2 + 255) & ~(size_t)255;    // N*64 fp16
  size_t o_h2    = (o_hr + (size_t)N * 64 * 2 + 255) & ~(size_t)255;    // N*16 fp16

  int* bcnt    = (int*)(ws + o_bcnt);
  int* bbase   = (int*)(ws + o_bbase);
  int* bcur    = (int*)(ws + o_bcur);
  __half* W1T  = (__half*)(ws + o_w1t);
  __half* W2T  = (__half*)(ws + o_w2t);
  float* dis   = (float*)(ws + o_dis);
  int* rowptr  = (int*)(ws + o_rowp);
  int* tmp     = (int*)(ws + o_tmp);
  int* csr     = (int*)(ws + o_csr);
  __half* h1   = (__half*)(ws + o_h1);
  __half* hr   = (__half*)(ws + o_hr);
  __half* h2   = (__half*)(ws + o_h2);

  hipMemsetAsync(bcnt, 0, MAXB * 4, stream);

  k_hist<<<256, 256, 0, stream>>>(dst, bcnt, E, nb);
  k_scanB<<<1, MAXB, 0, stream>>>(bcnt, bbase, bcur, nb);
  k_scatter<<<128, 256, 0, stream>>>(src, dst, bcur, tmp, E, nb);
  k_csr<<<nb, 256, 0, stream>>>(tmp, bbase, bcnt, csr, rowptr, dis, N);
  k_prepW<<<1, 256, 0, stream>>>(W1, W2, W1T, W2T);

  int gb = (N + 63) / 64;  // 1563
  k_gemm1<<<gb, 256, 0, stream>>>(x, W1T, dis, h1, N);
  k_agg1<<<((size_t)N * 64 + 255) / 256, 256, 0, stream>>>(h1, dis, rowptr, csr, b1, hr, N);
  k_gemm2<<<gb, 256, 0, stream>>>(hr, W2T, dis, h2, N);
  k_agg2<<<((size_t)N * 64 + 255) / 256, 256, 0, stream>>>(h2, dis, rowptr, csr, b2, out, N);
}

// Round 7
// 236.639 us; speedup vs baseline: 4.6560x; 1.0545x over previous
//
#include <hip/hip_runtime.h>
#include <hip/hip_bf16.h>
#include <hip/hip_fp16.h>

// GCN 2-layer: h1 = relu(A_hat (x@W1) + b1); out = log_softmax(A_hat (h1@W2) + b2)
// R7: block-major partition (each scatter block counting-sorts its chunk into its
// OWN dense region + segstart table; k_csr stitches segments). No k_hist pass.
// MFMA GEMMs, multi-substream wide-fp16 pull aggregation (R6).

#define F1 64
#define F2 16
#define MAXB 1024
#define BSH 128   // nodes per bucket; bucket = dst>>7, local = dst&127
#define NSB 256   // scatter blocks

typedef _Float16 f16x8 __attribute__((ext_vector_type(8)));
typedef _Float16 f16x4 __attribute__((ext_vector_type(4)));
typedef float f32x4 __attribute__((ext_vector_type(4)));

__device__ inline f16x8 shfl_xor_f16x8(f16x8 v, int off) {
  union U { f16x8 h; int i[4]; } a, b;
  a.h = v;
#pragma unroll
  for (int k = 0; k < 4; ++k) b.i[k] = __shfl_xor(a.i[k], off);
  return b.h;
}
__device__ inline f16x4 shfl_xor_f16x4(f16x4 v, int off) {
  union U { f16x4 h; int i[2]; } a, b;
  a.h = v;
#pragma unroll
  for (int k = 0; k < 2; ++k) b.i[k] = __shfl_xor(a.i[k], off);
  return b.h;
}

// ---- 1) per-block local counting sort into block-major tmp + segstart + bcnt ----
__global__ void k_scatterL(const int* __restrict__ src, const int* __restrict__ dst,
                           int* __restrict__ tmp, int* __restrict__ segstart,
                           int* __restrict__ bcnt, int E, int nb, int chunk) {
  __shared__ int h[MAXB];    // pass-1 counts
  __shared__ int cur[MAXB];  // scanned starts -> cursors
  __shared__ int sc[256];
  int t = threadIdx.x, sb = blockIdx.x;
  int beg = sb * chunk, end = min(beg + chunk, E);
  for (int i = t; i < MAXB; i += 256) h[i] = 0;
  __syncthreads();
  for (int e = beg + t * 4; e < end; e += 1024) {
    int4 d4 = *(const int4*)(dst + e);
    atomicAdd(&h[d4.x >> 7], 1);
    atomicAdd(&h[d4.y >> 7], 1);
    atomicAdd(&h[d4.z >> 7], 1);
    atomicAdd(&h[d4.w >> 7], 1);
  }
  __syncthreads();
  // flush global bucket counts (replaces old k_hist)
  for (int i = t; i < nb; i += 256)
    if (h[i]) atomicAdd(&bcnt[i], h[i]);
  // exclusive scan h[0..1023] -> cur (4 elems/thread)
  int i0 = t * 4;
  int l0 = h[i0], l1 = h[i0 + 1], l2 = h[i0 + 2], l3 = h[i0 + 3];
  sc[t] = l0 + l1 + l2 + l3;
  __syncthreads();
  for (int off = 1; off < 256; off <<= 1) {
    int a = (t >= off) ? sc[t - off] : 0;
    __syncthreads();
    sc[t] += a;
    __syncthreads();
  }
  int base = (t == 0) ? 0 : sc[t - 1];
  cur[i0] = base;
  cur[i0 + 1] = base + l0;
  cur[i0 + 2] = base + l0 + l1;
  cur[i0 + 3] = base + l0 + l1 + l2;
  __syncthreads();
  // emit segstart (global positions within this block's region)
  for (int i = t; i < nb; i += 256) segstart[sb * (nb + 1) + i] = beg + cur[i];
  if (t == 0) segstart[sb * (nb + 1) + nb] = end;
  __syncthreads();
  // pass 2: place packed edges densely in [beg, end)
  for (int e = beg + t * 4; e < end; e += 1024) {
    int4 d4 = *(const int4*)(dst + e);
    int4 s4 = *(const int4*)(src + e);
    int b, off;
    b = d4.x >> 7; off = atomicAdd(&cur[b], 1); tmp[beg + off] = (s4.x << 7) | (d4.x & 127);
    b = d4.y >> 7; off = atomicAdd(&cur[b], 1); tmp[beg + off] = (s4.y << 7) | (d4.y & 127);
    b = d4.z >> 7; off = atomicAdd(&cur[b], 1); tmp[beg + off] = (s4.z << 7) | (d4.z & 127);
    b = d4.w >> 7; off = atomicAdd(&cur[b], 1); tmp[beg + off] = (s4.w << 7) | (d4.w & 127);
  }
}

// ---- 2) exclusive scan of bucket counts -> bbase ----
__global__ void k_scanB(const int* __restrict__ bcnt, int* __restrict__ bbase, int nb) {
  __shared__ int lds[MAXB];
  int t = threadIdx.x;  // 1024 threads
  lds[t] = (t < nb) ? bcnt[t] : 0;
  __syncthreads();
  for (int off = 1; off < MAXB; off <<= 1) {
    int add = (t >= off) ? lds[t - off] : 0;
    __syncthreads();
    lds[t] += add;
    __syncthreads();
  }
  if (t < nb) bbase[t] = (t == 0) ? 0 : lds[t - 1];
}

// ---- 3) per-bucket sort (stitch 256 segments) -> csr + rowptr + dis ----
__global__ void k_csr(const int* __restrict__ tmp, const int* __restrict__ segstart,
                      const int* __restrict__ bbase, int* __restrict__ csr,
                      int* __restrict__ rowptr, float* __restrict__ dis,
                      int N, int nb) {
  __shared__ int cnt[BSH];
  __shared__ int sc[BSH];
  __shared__ int lofs[BSH];
  int b = blockIdx.x, t = threadIdx.x;
  if (t < BSH) cnt[t] = 0;
  __syncthreads();
  // thread t owns scatter-block t's segment for bucket b
  int s0 = segstart[t * (nb + 1) + b];
  int s1 = segstart[t * (nb + 1) + b + 1];
  for (int e = s0; e < s1; ++e) atomicAdd(&cnt[tmp[e] & 127], 1);
  __syncthreads();
  if (t < BSH) sc[t] = cnt[t];
  __syncthreads();
  for (int off = 1; off < BSH; off <<= 1) {
    int a = (t < BSH && t >= off) ? sc[t - off] : 0;
    __syncthreads();
    if (t < BSH) sc[t] += a;
    __syncthreads();
  }
  int beg = bbase[b];
  if (t < BSH) {
    int excl = (t == 0) ? 0 : sc[t - 1];
    lofs[t] = excl;
    int n = b * BSH + t;
    if (n <= N) rowptr[n] = beg + excl;  // n==N gets E
    if (n < N) dis[n] = rsqrtf((float)(cnt[t] + 1));
    cnt[t] = 0;  // reuse as cursor
  }
  __syncthreads();
  for (int e = s0; e < s1; ++e) {
    int p = tmp[e];
    int l = p & 127;
    int off = atomicAdd(&cnt[l], 1);
    csr[beg + lofs[l] + off] = p >> 7;
  }
}

// ---- prep: transpose weights to fp16 WT[n][k] ----
__global__ void k_prepW(const float* __restrict__ W1, const float* __restrict__ W2,
                        __half* __restrict__ W1T, __half* __restrict__ W2T) {
  int t = threadIdx.x;
  for (int i = t; i < 64 * 64; i += 256) {
    int n = i >> 6, k = i & 63;
    W1T[i] = __float2half(W1[k * 64 + n]);
  }
  for (int i = t; i < 16 * 64; i += 256) {
    int n = i >> 6, k = i & 63;
    W2T[i] = __float2half(W2[k * 16 + n]);
  }
}

// ---- GEMM1 (MFMA): h1[n] = fp16(dis[n] * (x[n] @ W1)); 64 rows/block ----
__global__ void k_gemm1(const float* __restrict__ x, const __half* __restrict__ W1T,
                        const float* __restrict__ dis, __half* __restrict__ out, int N) {
  int t = threadIdx.x;
  int wv = t >> 6, lane = t & 63;
  int m = lane & 15, q = lane >> 4;  // quad
  int row0 = blockIdx.x * 64 + wv * 16;
  int arow = min(row0 + m, N - 1);  // clamp for load safety
  const _Float16* wt = (const _Float16*)W1T;
  f16x8 bf[4][2];
#pragma unroll
  for (int c = 0; c < 4; ++c)
#pragma unroll
    for (int kt = 0; kt < 2; ++kt)
      bf[c][kt] = *(const f16x8*)&wt[(c * 16 + m) * 64 + kt * 32 + q * 8];
  f16x8 a[2];
#pragma unroll
  for (int kt = 0; kt < 2; ++kt) {
    const float4* xp = (const float4*)(x + (size_t)arow * 64 + kt * 32 + q * 8);
    float4 u = xp[0], v = xp[1];
    a[kt][0] = (_Float16)u.x; a[kt][1] = (_Float16)u.y;
    a[kt][2] = (_Float16)u.z; a[kt][3] = (_Float16)u.w;
    a[kt][4] = (_Float16)v.x; a[kt][5] = (_Float16)v.y;
    a[kt][6] = (_Float16)v.z; a[kt][7] = (_Float16)v.w;
  }
  f32x4 acc[4] = {};
#pragma unroll
  for (int kt = 0; kt < 2; ++kt)
#pragma unroll
    for (int c = 0; c < 4; ++c)
      acc[c] = __builtin_amdgcn_mfma_f32_16x16x32_f16(a[kt], bf[c][kt], acc[c], 0, 0, 0);
#pragma unroll
  for (int r = 0; r < 4; ++r) {
    int n = row0 + q * 4 + r;
    if (n < N) {
      float dn = dis[n];
#pragma unroll
      for (int c = 0; c < 4; ++c)
        out[(size_t)n * 64 + c * 16 + m] = __float2half(acc[c][r] * dn);
    }
  }
}

// ---- agg layer 1: wave/node; 8 substreams x 8 lanes x 16B gathers ----
__global__ void k_agg1(const __half* __restrict__ h, const float* __restrict__ dis,
                       const int* __restrict__ rowptr, const int* __restrict__ csr,
                       const float* __restrict__ b1, __half* __restrict__ out, int N) {
  int gt = blockIdx.x * blockDim.x + threadIdx.x;
  int n = gt >> 6;
  if (n >= N) return;
  int lane = gt & 63;
  int fl = lane & 7;    // feature-octet lane
  int sub = lane >> 3;  // edge substream
  const _Float16* hp = (const _Float16*)h;
  f16x8 acc = {};
  if (sub == 0)  // self loop (rows pre-scaled by dis)
    acc = *(const f16x8*)&hp[(size_t)n * 64 + fl * 8];
  int beg = rowptr[n], end = rowptr[n + 1];
  for (int e = beg + sub; e < end; e += 8) {
    int s = csr[e];
    f16x8 v = *(const f16x8*)&hp[(size_t)s * 64 + fl * 8];
    acc += v;
  }
  acc += shfl_xor_f16x8(acc, 8);
  acc += shfl_xor_f16x8(acc, 16);
  acc += shfl_xor_f16x8(acc, 32);
  if (sub == 0) {
    float dn = dis[n];
    float4 bu = *(const float4*)(b1 + fl * 8);
    float4 bv = *(const float4*)(b1 + fl * 8 + 4);
    float bb[8] = {bu.x, bu.y, bu.z, bu.w, bv.x, bv.y, bv.z, bv.w};
    f16x8 o;
#pragma unroll
    for (int k = 0; k < 8; ++k) {
      float v = fmaf(dn, (float)acc[k], bb[k]);
      o[k] = (_Float16)fmaxf(v, 0.f);
    }
    *(f16x8*)((_Float16*)out + (size_t)n * 64 + fl * 8) = o;
  }
}

// ---- GEMM2 (MFMA): h2[n] = fp16(dis[n] * (hr[n] @ W2)); 64 rows/block ----
__global__ void k_gemm2(const __half* __restrict__ hr, const __half* __restrict__ W2T,
                        const float* __restrict__ dis, __half* __restrict__ out, int N) {
  int t = threadIdx.x;
  int wv = t >> 6, lane = t & 63;
  int m = lane & 15, q = lane >> 4;
  int row0 = blockIdx.x * 64 + wv * 16;
  int arow = min(row0 + m, N - 1);
  const _Float16* wt = (const _Float16*)W2T;
  f32x4 acc = {};
#pragma unroll
  for (int kt = 0; kt < 2; ++kt) {
    f16x8 a = *(const f16x8*)((const _Float16*)hr + (size_t)arow * 64 + kt * 32 + q * 8);
    f16x8 bfrag = *(const f16x8*)&wt[m * 64 + kt * 32 + q * 8];
    acc = __builtin_amdgcn_mfma_f32_16x16x32_f16(a, bfrag, acc, 0, 0, 0);
  }
#pragma unroll
  for (int r = 0; r < 4; ++r) {
    int n = row0 + q * 4 + r;
    if (n < N)
      out[(size_t)n * 16 + m] = __float2half(acc[r] * dis[n]);
  }
}

// ---- agg layer 2 + bias + log_softmax: wave/node; 16 subs x 4 lanes x 8B ----
__global__ void k_agg2(const __half* __restrict__ h2, const float* __restrict__ dis,
                       const int* __restrict__ rowptr, const int* __restrict__ csr,
                       const float* __restrict__ b2, float* __restrict__ out, int N) {
  int gt = blockIdx.x * blockDim.x + threadIdx.x;
  int n = gt >> 6;
  if (n >= N) return;
  int lane = gt & 63;
  int fl = lane & 3;    // feature-quad lane
  int sub = lane >> 2;  // 16 edge substreams
  const _Float16* hp = (const _Float16*)h2;
  f16x4 acc = {};
  if (sub == 0)  // self loop
    acc = *(const f16x4*)&hp[(size_t)n * 16 + fl * 4];
  int beg = rowptr[n], end = rowptr[n + 1];
  for (int e = beg + sub; e < end; e += 16) {
    int s = csr[e];
    f16x4 v = *(const f16x4*)&hp[(size_t)s * 16 + fl * 4];
    acc += v;
  }
  acc += shfl_xor_f16x4(acc, 4);
  acc += shfl_xor_f16x4(acc, 8);
  acc += shfl_xor_f16x4(acc, 16);
  acc += shfl_xor_f16x4(acc, 32);
  if (sub == 0) {
    float dn = dis[n];
    float4 bb = *(const float4*)(b2 + fl * 4);
    float v0 = fmaf(dn, (float)acc[0], bb.x);
    float v1 = fmaf(dn, (float)acc[1], bb.y);
    float v2 = fmaf(dn, (float)acc[2], bb.z);
    float v3 = fmaf(dn, (float)acc[3], bb.w);
    float m = fmaxf(fmaxf(v0, v1), fmaxf(v2, v3));
    m = fmaxf(m, __shfl_xor(m, 1));
    m = fmaxf(m, __shfl_xor(m, 2));
    float s = __expf(v0 - m) + __expf(v1 - m) + __expf(v2 - m) + __expf(v3 - m);
    s += __shfl_xor(s, 1);
    s += __shfl_xor(s, 2);
    float ls = m + __logf(s);
    float4 o = {v0 - ls, v1 - ls, v2 - ls, v3 - ls};
    *(float4*)(out + (size_t)n * 16 + fl * 4) = o;
  }
}

extern "C" void kernel_launch(void* const* d_in, const int* in_sizes, int n_in,
                              void* d_out, int out_size, void* d_ws, size_t ws_size,
                              hipStream_t stream) {
  const float* x = (const float*)d_in[0];
  const int* ei = (const int*)d_in[1];
  const float* W1 = (const float*)d_in[2];
  const float* b1 = (const float*)d_in[3];
  const float* W2 = (const float*)d_in[4];
  const float* b2 = (const float*)d_in[5];
  float* out = (float*)d_out;

  int N = in_sizes[0] / F1;  // 100000
  int E = in_sizes[1] / 2;   // 1600000
  const int* src = ei;
  const int* dst = ei + E;
  int nb = (N + BSH - 1) >> 7;  // 782 buckets
  int chunk = ((E + NSB - 1) / NSB + 3) & ~3;  // 6252, multiple of 4

  char* ws = (char*)d_ws;
  size_t o_bcnt  = 0;                                        // MAXB int
  size_t o_bbase = o_bcnt + MAXB * 4;
  size_t o_w1t   = o_bbase + MAXB * 4;                       // 64*64 fp16
  size_t o_w2t   = o_w1t + 64 * 64 * 2;                      // 16*64 fp16
  size_t o_seg   = (o_w2t + 16 * 64 * 2 + 255) & ~(size_t)255;          // NSB*(nb+1) int
  size_t o_dis   = (o_seg + (size_t)NSB * (nb + 1) * 4 + 255) & ~(size_t)255;  // N f32
  size_t o_rowp  = (o_dis + (size_t)N * 4 + 255) & ~(size_t)255;        // N+1 int
  size_t o_tmp   = (o_rowp + (size_t)(N + 1) * 4 + 255) & ~(size_t)255; // NSB*chunk int
  size_t o_csr   = (o_tmp + (size_t)NSB * chunk * 4 + 255) & ~(size_t)255;  // E int
  size_t o_h1    = (o_csr + (size_t)E * 4 + 255) & ~(size_t)255;        // N*64 fp16
  size_t o_hr    = (o_h1 + (size_t)N * 64 * 2 + 255) & ~(size_t)255;    // N*64 fp16
  size_t o_h2    = (o_hr + (size_t)N * 64 * 2 + 255) & ~(size_t)255;    // N*16 fp16

  int* bcnt    = (int*)(ws + o_bcnt);
  int* bbase   = (int*)(ws + o_bbase);
  __half* W1T  = (__half*)(ws + o_w1t);
  __half* W2T  = (__half*)(ws + o_w2t);
  int* segst   = (int*)(ws + o_seg);
  float* dis   = (float*)(ws + o_dis);
  int* rowptr  = (int*)(ws + o_rowp);
  int* tmp     = (int*)(ws + o_tmp);
  int* csr     = (int*)(ws + o_csr);
  __half* h1   = (__half*)(ws + o_h1);
  __half* hr   = (__half*)(ws + o_hr);
  __half* h2   = (__half*)(ws + o_h2);

  hipMemsetAsync(bcnt, 0, MAXB * 4, stream);

  k_scatterL<<<NSB, 256, 0, stream>>>(src, dst, tmp, segst, bcnt, E, nb, chunk);
  k_scanB<<<1, MAXB, 0, stream>>>(bcnt, bbase, nb);
  k_csr<<<nb, 256, 0, stream>>>(tmp, segst, bbase, csr, rowptr, dis, N, nb);
  k_prepW<<<1, 256, 0, stream>>>(W1, W2, W1T, W2T);

  int gb = (N + 63) / 64;  // 1563
  k_gemm1<<<gb, 256, 0, stream>>>(x, W1T, dis, h1, N);
  k_agg1<<<((size_t)N * 64 + 255) / 256, 256, 0, stream>>>(h1, dis, rowptr, csr, b1, hr, N);
  k_gemm2<<<gb, 256, 0, stream>>>(hr, W2T, dis, h2, N);
  k_agg2<<<((size_t)N * 64 + 255) / 256, 256, 0, stream>>>(h2, dis, rowptr, csr, b2, out, N);
}

// Round 8
// 219.906 us; speedup vs baseline: 5.0103x; 1.0761x over previous
//
#include <hip/hip_runtime.h>
#include <hip/hip_bf16.h>
#include <hip/hip_fp16.h>

// GCN 2-layer: h1 = relu(A_hat (x@W1) + b1); out = log_softmax(A_hat (h1@W2) + b2)
// R8: gemm2 fused into agg1's epilogue (allreduced row -> per-sub 2-output dot,
// writes h2 directly; hr buffer eliminated). Software-pipelined csr->gather in
// both agg loops. 512-thread scatter blocks. scanB+prepW merged.

#define F1 64
#define F2 16
#define MAXB 1024
#define BSH 128   // nodes per bucket; bucket = dst>>7, local = dst&127
#define NSB 256   // scatter blocks (== k_csr threads)
#define SBD 512   // scatter block dim

typedef _Float16 f16x8 __attribute__((ext_vector_type(8)));
typedef _Float16 f16x4 __attribute__((ext_vector_type(4)));
typedef float f32x4 __attribute__((ext_vector_type(4)));

__device__ inline f16x8 shfl_xor_f16x8(f16x8 v, int off) {
  union U { f16x8 h; int i[4]; } a, b;
  a.h = v;
#pragma unroll
  for (int k = 0; k < 4; ++k) b.i[k] = __shfl_xor(a.i[k], off);
  return b.h;
}
__device__ inline f16x4 shfl_xor_f16x4(f16x4 v, int off) {
  union U { f16x4 h; int i[2]; } a, b;
  a.h = v;
#pragma unroll
  for (int k = 0; k < 2; ++k) b.i[k] = __shfl_xor(a.i[k], off);
  return b.h;
}

// ---- 1) per-block local counting sort into block-major tmp + segstart + bcnt ----
__global__ void k_scatterL(const int* __restrict__ src, const int* __restrict__ dst,
                           int* __restrict__ tmp, int* __restrict__ segstart,
                           int* __restrict__ bcnt, int E, int nb, int chunk) {
  __shared__ int h[MAXB];    // pass-1 counts
  __shared__ int cur[MAXB];  // scanned starts -> cursors
  __shared__ int sc[SBD];
  int t = threadIdx.x, sb = blockIdx.x;
  int beg = sb * chunk, end = min(beg + chunk, E);
  for (int i = t; i < MAXB; i += SBD) h[i] = 0;
  __syncthreads();
  int e;
  for (e = beg + t * 4; e + 4 <= end; e += 4 * SBD) {
    int4 d4 = *(const int4*)(dst + e);
    atomicAdd(&h[d4.x >> 7], 1);
    atomicAdd(&h[d4.y >> 7], 1);
    atomicAdd(&h[d4.z >> 7], 1);
    atomicAdd(&h[d4.w >> 7], 1);
  }
  for (; e < end; ++e) atomicAdd(&h[dst[e] >> 7], 1);
  __syncthreads();
  for (int i = t; i < nb; i += SBD)
    if (h[i]) atomicAdd(&bcnt[i], h[i]);
  // exclusive scan h[0..1023] -> cur (2 bins/thread)
  int i0 = t * 2;
  int l0 = h[i0], l1 = h[i0 + 1];
  sc[t] = l0 + l1;
  __syncthreads();
  for (int off = 1; off < SBD; off <<= 1) {
    int a = (t >= off) ? sc[t - off] : 0;
    __syncthreads();
    sc[t] += a;
    __syncthreads();
  }
  int base = (t == 0) ? 0 : sc[t - 1];
  cur[i0] = base;
  cur[i0 + 1] = base + l0;
  __syncthreads();
  for (int i = t; i < nb; i += SBD) segstart[sb * (nb + 1) + i] = beg + cur[i];
  if (t == 0) segstart[sb * (nb + 1) + nb] = end;
  __syncthreads();
  // pass 2: place packed edges densely in [beg, end)
  for (e = beg + t * 4; e + 4 <= end; e += 4 * SBD) {
    int4 d4 = *(const int4*)(dst + e);
    int4 s4 = *(const int4*)(src + e);
    int b, off;
    b = d4.x >> 7; off = atomicAdd(&cur[b], 1); tmp[beg + off] = (s4.x << 7) | (d4.x & 127);
    b = d4.y >> 7; off = atomicAdd(&cur[b], 1); tmp[beg + off] = (s4.y << 7) | (d4.y & 127);
    b = d4.z >> 7; off = atomicAdd(&cur[b], 1); tmp[beg + off] = (s4.z << 7) | (d4.z & 127);
    b = d4.w >> 7; off = atomicAdd(&cur[b], 1); tmp[beg + off] = (s4.w << 7) | (d4.w & 127);
  }
  for (; e < end; ++e) {
    int d = dst[e];
    int b = d >> 7;
    int off = atomicAdd(&cur[b], 1);
    tmp[beg + off] = (src[e] << 7) | (d & 127);
  }
}

// ---- 2) block 0: scan bucket counts -> bbase; block 1: fp16 weight transpose ----
__global__ void k_misc(const int* __restrict__ bcnt, int* __restrict__ bbase, int nb,
                       const float* __restrict__ W1, const float* __restrict__ W2,
                       __half* __restrict__ W1T, __half* __restrict__ W2T) {
  int t = threadIdx.x;  // 1024
  if (blockIdx.x == 0) {
    __shared__ int lds[MAXB];
    lds[t] = (t < nb) ? bcnt[t] : 0;
    __syncthreads();
    for (int off = 1; off < MAXB; off <<= 1) {
      int add = (t >= off) ? lds[t - off] : 0;
      __syncthreads();
      lds[t] += add;
      __syncthreads();
    }
    if (t < nb) bbase[t] = (t == 0) ? 0 : lds[t - 1];
  } else {
    for (int i = t; i < 64 * 64; i += 1024) {
      int n = i >> 6, k = i & 63;
      W1T[i] = __float2half(W1[k * 64 + n]);
    }
    for (int i = t; i < 16 * 64; i += 1024) {
      int n = i >> 6, k = i & 63;
      W2T[i] = __float2half(W2[k * 16 + n]);
    }
  }
}

// ---- 3) per-bucket sort (stitch 256 segments) -> csr + rowptr + dis ----
__global__ void k_csr(const int* __restrict__ tmp, const int* __restrict__ segstart,
                      const int* __restrict__ bbase, int* __restrict__ csr,
                      int* __restrict__ rowptr, float* __restrict__ dis,
                      int N, int nb) {
  __shared__ int cnt[BSH];
  __shared__ int sc[BSH];
  __shared__ int lofs[BSH];
  int b = blockIdx.x, t = threadIdx.x;
  if (t < BSH) cnt[t] = 0;
  __syncthreads();
  int s0 = segstart[t * (nb + 1) + b];
  int s1 = segstart[t * (nb + 1) + b + 1];
  for (int e = s0; e < s1; ++e) atomicAdd(&cnt[tmp[e] & 127], 1);
  __syncthreads();
  if (t < BSH) sc[t] = cnt[t];
  __syncthreads();
  for (int off = 1; off < BSH; off <<= 1) {
    int a = (t < BSH && t >= off) ? sc[t - off] : 0;
    __syncthreads();
    if (t < BSH) sc[t] += a;
    __syncthreads();
  }
  int beg = bbase[b];
  if (t < BSH) {
    int excl = (t == 0) ? 0 : sc[t - 1];
    lofs[t] = excl;
    int n = b * BSH + t;
    if (n <= N) rowptr[n] = beg + excl;  // n==N gets E
    if (n < N) dis[n] = rsqrtf((float)(cnt[t] + 1));
    cnt[t] = 0;  // reuse as cursor
  }
  __syncthreads();
  for (int e = s0; e < s1; ++e) {
    int p = tmp[e];
    int l = p & 127;
    int off = atomicAdd(&cnt[l], 1);
    csr[beg + lofs[l] + off] = p >> 7;
  }
}

// ---- GEMM1 (MFMA): h1[n] = fp16(dis[n] * (x[n] @ W1)); 64 rows/block ----
__global__ void k_gemm1(const float* __restrict__ x, const __half* __restrict__ W1T,
                        const float* __restrict__ dis, __half* __restrict__ out, int N) {
  int t = threadIdx.x;
  int wv = t >> 6, lane = t & 63;
  int m = lane & 15, q = lane >> 4;  // quad
  int row0 = blockIdx.x * 64 + wv * 16;
  int arow = min(row0 + m, N - 1);  // clamp for load safety
  const _Float16* wt = (const _Float16*)W1T;
  f16x8 bf[4][2];
#pragma unroll
  for (int c = 0; c < 4; ++c)
#pragma unroll
    for (int kt = 0; kt < 2; ++kt)
      bf[c][kt] = *(const f16x8*)&wt[(c * 16 + m) * 64 + kt * 32 + q * 8];
  f16x8 a[2];
#pragma unroll
  for (int kt = 0; kt < 2; ++kt) {
    const float4* xp = (const float4*)(x + (size_t)arow * 64 + kt * 32 + q * 8);
    float4 u = xp[0], v = xp[1];
    a[kt][0] = (_Float16)u.x; a[kt][1] = (_Float16)u.y;
    a[kt][2] = (_Float16)u.z; a[kt][3] = (_Float16)u.w;
    a[kt][4] = (_Float16)v.x; a[kt][5] = (_Float16)v.y;
    a[kt][6] = (_Float16)v.z; a[kt][7] = (_Float16)v.w;
  }
  f32x4 acc[4] = {};
#pragma unroll
  for (int kt = 0; kt < 2; ++kt)
#pragma unroll
    for (int c = 0; c < 4; ++c)
      acc[c] = __builtin_amdgcn_mfma_f32_16x16x32_f16(a[kt], bf[c][kt], acc[c], 0, 0, 0);
#pragma unroll
  for (int r = 0; r < 4; ++r) {
    int n = row0 + q * 4 + r;
    if (n < N) {
      float dn = dis[n];
#pragma unroll
      for (int c = 0; c < 4; ++c)
        out[(size_t)n * 64 + c * 16 + m] = __float2half(acc[c][r] * dn);
    }
  }
}

// ---- agg layer 1 + fused GEMM2: wave/node ----
// Edge loop: 8 subs x 8 fl-lanes x 16B gathers, pipelined csr loads.
// Epilogue: xor-butterfly ALLreduce -> every lane holds the row; relu+bias in
// fp32; each sub computes outputs j=sub*2,sub*2+1 of hr@W2 (16 fmaf), reduce
// over fl, write h2[n] = fp16(dis[n] * (hr@W2)) directly.
__global__ void k_agg1f(const __half* __restrict__ h, const float* __restrict__ dis,
                        const int* __restrict__ rowptr, const int* __restrict__ csr,
                        const float* __restrict__ b1, const __half* __restrict__ W2T,
                        __half* __restrict__ h2, int N) {
  int gt = blockIdx.x * blockDim.x + threadIdx.x;
  int n = gt >> 6;
  if (n >= N) return;
  int lane = gt & 63;
  int fl = lane & 7;    // feature-octet lane
  int sub = lane >> 3;  // edge substream / output pair
  const _Float16* hp = (const _Float16*)h;
  // independent preloads (overlap with edge loop)
  float dn = dis[n];
  float4 bu = *(const float4*)(b1 + fl * 8);
  float4 bv = *(const float4*)(b1 + fl * 8 + 4);
  const _Float16* wt = (const _Float16*)W2T;
  f16x8 w0 = *(const f16x8*)&wt[(sub * 2 + 0) * 64 + fl * 8];
  f16x8 w1 = *(const f16x8*)&wt[(sub * 2 + 1) * 64 + fl * 8];
  f16x8 acc = {};
  if (sub == 0)  // self loop (rows pre-scaled by dis)
    acc = *(const f16x8*)&hp[(size_t)n * 64 + fl * 8];
  int beg = rowptr[n], end = rowptr[n + 1];
  // software-pipelined: csr index for iter k+1 in flight with gather of iter k
  int e = beg + sub;
  int s = (e < end) ? csr[e] : -1;
  while (s >= 0) {
    int e2 = e + 8;
    int s2 = (e2 < end) ? csr[e2] : -1;
    f16x8 v = *(const f16x8*)&hp[(size_t)s * 64 + fl * 8];
    acc += v;
    e = e2; s = s2;
  }
  // allreduce across 8 substreams
  acc += shfl_xor_f16x8(acc, 8);
  acc += shfl_xor_f16x8(acc, 16);
  acc += shfl_xor_f16x8(acc, 32);
  // relu + bias in fp32 (every lane has the row fragment for its fl)
  float bb[8] = {bu.x, bu.y, bu.z, bu.w, bv.x, bv.y, bv.z, bv.w};
  float hrow[8];
#pragma unroll
  for (int k = 0; k < 8; ++k)
    hrow[k] = fmaxf(fmaf(dn, (float)acc[k], bb[k]), 0.f);
  // fused gemm2: partial dots for outputs j0=sub*2, j1=sub*2+1
  float p0 = 0.f, p1 = 0.f;
#pragma unroll
  for (int k = 0; k < 8; ++k) {
    p0 = fmaf(hrow[k], (float)w0[k], p0);
    p1 = fmaf(hrow[k], (float)w1[k], p1);
  }
  p0 += __shfl_xor(p0, 1); p1 += __shfl_xor(p1, 1);
  p0 += __shfl_xor(p0, 2); p1 += __shfl_xor(p1, 2);
  p0 += __shfl_xor(p0, 4); p1 += __shfl_xor(p1, 4);
  if (fl == 0) {
    __half2 o;
    o.x = __float2half(p0 * dn);
    o.y = __float2half(p1 * dn);
    *(__half2*)((_Float16*)h2 + (size_t)n * 16 + sub * 2) = o;
  }
}

// ---- agg layer 2 + bias + log_softmax: wave/node; 16 subs x 4 lanes x 8B ----
__global__ void k_agg2(const __half* __restrict__ h2, const float* __restrict__ dis,
                       const int* __restrict__ rowptr, const int* __restrict__ csr,
                       const float* __restrict__ b2, float* __restrict__ out, int N) {
  int gt = blockIdx.x * blockDim.x + threadIdx.x;
  int n = gt >> 6;
  if (n >= N) return;
  int lane = gt & 63;
  int fl = lane & 3;    // feature-quad lane
  int sub = lane >> 2;  // 16 edge substreams
  const _Float16* hp = (const _Float16*)h2;
  f16x4 acc = {};
  if (sub == 0)  // self loop
    acc = *(const f16x4*)&hp[(size_t)n * 16 + fl * 4];
  int beg = rowptr[n], end = rowptr[n + 1];
  int e = beg + sub;
  int s = (e < end) ? csr[e] : -1;
  while (s >= 0) {
    int e2 = e + 16;
    int s2 = (e2 < end) ? csr[e2] : -1;
    f16x4 v = *(const f16x4*)&hp[(size_t)s * 16 + fl * 4];
    acc += v;
    e = e2; s = s2;
  }
  acc += shfl_xor_f16x4(acc, 4);
  acc += shfl_xor_f16x4(acc, 8);
  acc += shfl_xor_f16x4(acc, 16);
  acc += shfl_xor_f16x4(acc, 32);
  if (sub == 0) {
    float dn = dis[n];
    float4 bb = *(const float4*)(b2 + fl * 4);
    float v0 = fmaf(dn, (float)acc[0], bb.x);
    float v1 = fmaf(dn, (float)acc[1], bb.y);
    float v2 = fmaf(dn, (float)acc[2], bb.z);
    float v3 = fmaf(dn, (float)acc[3], bb.w);
    float m = fmaxf(fmaxf(v0, v1), fmaxf(v2, v3));
    m = fmaxf(m, __shfl_xor(m, 1));
    m = fmaxf(m, __shfl_xor(m, 2));
    float s2 = __expf(v0 - m) + __expf(v1 - m) + __expf(v2 - m) + __expf(v3 - m);
    s2 += __shfl_xor(s2, 1);
    s2 += __shfl_xor(s2, 2);
    float ls = m + __logf(s2);
    float4 o = {v0 - ls, v1 - ls, v2 - ls, v3 - ls};
    *(float4*)(out + (size_t)n * 16 + fl * 4) = o;
  }
}

extern "C" void kernel_launch(void* const* d_in, const int* in_sizes, int n_in,
                              void* d_out, int out_size, void* d_ws, size_t ws_size,
                              hipStream_t stream) {
  const float* x = (const float*)d_in[0];
  const int* ei = (const int*)d_in[1];
  const float* W1 = (const float*)d_in[2];
  const float* b1 = (const float*)d_in[3];
  const float* W2 = (const float*)d_in[4];
  const float* b2 = (const float*)d_in[5];
  float* out = (float*)d_out;

  int N = in_sizes[0] / F1;  // 100000
  int E = in_sizes[1] / 2;   // 1600000
  const int* src = ei;
  const int* dst = ei + E;
  int nb = (N + BSH - 1) >> 7;  // 782 buckets
  int chunk = ((E + NSB - 1) / NSB + 3) & ~3;  // multiple of 4

  char* ws = (char*)d_ws;
  size_t o_bcnt  = 0;                                        // MAXB int
  size_t o_bbase = o_bcnt + MAXB * 4;
  size_t o_w1t   = o_bbase + MAXB * 4;                       // 64*64 fp16
  size_t o_w2t   = o_w1t + 64 * 64 * 2;                      // 16*64 fp16
  size_t o_seg   = (o_w2t + 16 * 64 * 2 + 255) & ~(size_t)255;          // NSB*(nb+1) int
  size_t o_dis   = (o_seg + (size_t)NSB * (nb + 1) * 4 + 255) & ~(size_t)255;  // N f32
  size_t o_rowp  = (o_dis + (size_t)N * 4 + 255) & ~(size_t)255;        // N+1 int
  size_t o_tmp   = (o_rowp + (size_t)(N + 1) * 4 + 255) & ~(size_t)255; // NSB*chunk int
  size_t o_csr   = (o_tmp + (size_t)NSB * chunk * 4 + 255) & ~(size_t)255;  // E int
  size_t o_h1    = (o_csr + (size_t)E * 4 + 255) & ~(size_t)255;        // N*64 fp16
  size_t o_h2    = (o_h1 + (size_t)N * 64 * 2 + 255) & ~(size_t)255;    // N*16 fp16

  int* bcnt    = (int*)(ws + o_bcnt);
  int* bbase   = (int*)(ws + o_bbase);
  __half* W1T  = (__half*)(ws + o_w1t);
  __half* W2T  = (__half*)(ws + o_w2t);
  int* segst   = (int*)(ws + o_seg);
  float* dis   = (float*)(ws + o_dis);
  int* rowptr  = (int*)(ws + o_rowp);
  int* tmp     = (int*)(ws + o_tmp);
  int* csr     = (int*)(ws + o_csr);
  __half* h1   = (__half*)(ws + o_h1);
  __half* h2   = (__half*)(ws + o_h2);

  hipMemsetAsync(bcnt, 0, MAXB * 4, stream);

  k_scatterL<<<NSB, SBD, 0, stream>>>(src, dst, tmp, segst, bcnt, E, nb, chunk);
  k_misc<<<2, MAXB, 0, stream>>>(bcnt, bbase, nb, W1, W2, W1T, W2T);
  k_csr<<<nb, 256, 0, stream>>>(tmp, segst, bbase, csr, rowptr, dis, N, nb);

  int gb = (N + 63) / 64;  // 1563
  k_gemm1<<<gb, 256, 0, stream>>>(x, W1T, dis, h1, N);
  k_agg1f<<<((size_t)N * 64 + 255) / 256, 256, 0, stream>>>(h1, dis, rowptr, csr, b1, W2T, h2, N);
  k_agg2<<<((size_t)N * 64 + 255) / 256, 256, 0, stream>>>(h2, dis, rowptr, csr, b2, out, N);
}